// Round 10
// baseline (144.390 us; speedup 1.0000x reference)
//
#include <hip/hip_runtime.h>
#include <hip/hip_fp8.h>

#define NV 4
#define NB 2048
#define ND 512
#define NN 8192
// sim = cos/TEMP, TEMP=0.5 -> scale 2.0

typedef int int8v __attribute__((ext_vector_type(8)));
typedef int int4v __attribute__((ext_vector_type(4)));
typedef float floatx4 __attribute__((ext_vector_type(4)));
#define SCALE1 0x7F7F7F7Fu  // E8M0 bytes 127 -> 2^0 = 1.0

// ============================================================================
// R17 = R16's 2-deep pipeline with R14-PROVEN fragment assembly.
// R16 failed in the container twice; audit cleared addressing/grid (all
// in-bounds, same as passing R14). Prime suspect: LD8 took the ADDRESS of a
// register ext_vector local and stored int4v halves through it (type-punned
// partial writes feeding MFMA operands) — a plausible hipcc ISel/regalloc
// breaker. This version keeps the schedule but builds fragments the R14 way:
// two int4v temporaries + __builtin_shufflevector (compiled & passed at
// 48.5 µs in R14/R15).
// Schedule: two NAMED fragment sets (rule #20), loads of kt+1 issued BEFORE
// kt's MFMA16 -> compiler's auto-waitcnt becomes vmcnt(16) not vmcnt(0);
// steady-state L2 latency hides under the MFMA cluster. ~230 VGPR,
// __launch_bounds__(256,2). Tripwire: WRITE_SIZE must stay ~4.4 MB.
// ============================================================================

// ---------------- normalize: x[N,D] f32 -> xn fragment-layout fp8 ----------
// fragment layout: xn[R][C][m][b] (R=row>>4, C=k>>5, m=row&15, b=k&31),
// linear = R*8192 + C*512 + m*32 + b. A wave's MFMA operand is 2 KB
// contiguous -> loaded straight from global (4 MB, L2-resident).
__global__ __launch_bounds__(256) void normalize_k(const float* __restrict__ x,
                                                   unsigned char* __restrict__ xn,
                                                   float* __restrict__ sumexp,
                                                   float* __restrict__ out) {
  if (threadIdx.x < 4) sumexp[blockIdx.x * 4 + threadIdx.x] = 0.0f;
  if (blockIdx.x == 0 && threadIdx.x == 0) out[0] = 0.0f;

  const int row = blockIdx.x * 4 + (threadIdx.x >> 6);  // one wave per row
  const int l = threadIdx.x & 63;                        // lane: cols [8l, 8l+8)
  const float4* xr = (const float4*)(x + (size_t)row * ND);
  float4 v0 = xr[l * 2 + 0];
  float4 v1 = xr[l * 2 + 1];
  float ss = v0.x * v0.x + v0.y * v0.y + v0.z * v0.z + v0.w * v0.w +
             v1.x * v1.x + v1.y * v1.y + v1.z * v1.z + v1.w * v1.w;
#pragma unroll
  for (int off = 32; off > 0; off >>= 1) ss += __shfl_xor(ss, off, 64);
  const float inv = 1.0f / fmaxf(sqrtf(ss), 1e-8f);
  union { unsigned char b[8]; uint2 u; } pk;
  pk.b[0] = __hip_fp8_e4m3(v0.x * inv).__x;
  pk.b[1] = __hip_fp8_e4m3(v0.y * inv).__x;
  pk.b[2] = __hip_fp8_e4m3(v0.z * inv).__x;
  pk.b[3] = __hip_fp8_e4m3(v0.w * inv).__x;
  pk.b[4] = __hip_fp8_e4m3(v1.x * inv).__x;
  pk.b[5] = __hip_fp8_e4m3(v1.y * inv).__x;
  pk.b[6] = __hip_fp8_e4m3(v1.z * inv).__x;
  pk.b[7] = __hip_fp8_e4m3(v1.w * inv).__x;
  // k-bytes [8l,8l+8) -> chunk C=l>>2, intra b=(l&3)*8
  const int R = row >> 4, mm = row & 15;
  *(uint2*)(xn + (size_t)R * 8192 + (l >> 2) * 512 + mm * 32 + (l & 3) * 8) =
      pk.u;
}

// ---------------- sim: LDS-free, pipelined direct-fragment GEMM ------------
__global__ __launch_bounds__(256, 2) void sim_k(const unsigned char* __restrict__ xn,
                                                float* __restrict__ sumexp,
                                                float* __restrict__ pos) {
  const int tid = threadIdx.x;
  const int l = tid & 63;
  const int m = l & 15, q = l >> 4;
  const int wr = (tid >> 6) >> 1, wc = (tid >> 6) & 1;

  // XCD swizzle (2080 = 8*260, bijective) for L2 locality
  const int bid = (blockIdx.x & 7) * 260 + (blockIdx.x >> 3);
  // triangular decode: bid -> (rt, ct), rt <= ct
  int rt = (int)((129.0f - sqrtf(16641.0f - 8.0f * (float)bid)) * 0.5f);
  rt = rt < 0 ? 0 : (rt > 63 ? 63 : rt);
  while (rt > 0 && (rt * 64 - rt * (rt - 1) / 2) > bid) --rt;
  while (rt < 63 && ((rt + 1) * 64 - (rt + 1) * rt / 2) <= bid) ++rt;
  const int ct = rt + (bid - (rt * 64 - rt * (rt - 1) / 2));
  const bool diag = (rt == ct);

  floatx4 acc[4][4] = {};

  // lane base inside a fragment block: chunk q (512 B), row m (32 B)
  const unsigned char* pa =
      xn + (size_t)(rt * 8 + wr * 4) * 8192 + q * 512 + m * 32;
  const unsigned char* pb =
      xn + (size_t)(ct * 8 + wc * 4) * 8192 + q * 512 + m * 32;

  // R14-proven fragment assembly: two int4v loads + shufflevector join
#define LD8(dst, base, mt, kt)                                               \
  do {                                                                       \
    const unsigned char* p_ = (base) + (mt) * 8192 + (kt) * 2048;            \
    int4v lo_ = *(const int4v*)(p_);                                         \
    int4v hi_ = *(const int4v*)(p_ + 16);                                    \
    dst = __builtin_shufflevector(lo_, hi_, 0, 1, 2, 3, 4, 5, 6, 7);         \
  } while (0)

#define MFMA16(A0, A1, A2, A3, B0, B1, B2, B3)                               \
  do {                                                                       \
    acc[0][0] = __builtin_amdgcn_mfma_scale_f32_16x16x128_f8f6f4(            \
        A0, B0, acc[0][0], 0, 0, 0, SCALE1, 0, SCALE1);                      \
    acc[0][1] = __builtin_amdgcn_mfma_scale_f32_16x16x128_f8f6f4(            \
        A0, B1, acc[0][1], 0, 0, 0, SCALE1, 0, SCALE1);                      \
    acc[0][2] = __builtin_amdgcn_mfma_scale_f32_16x16x128_f8f6f4(            \
        A0, B2, acc[0][2], 0, 0, 0, SCALE1, 0, SCALE1);                      \
    acc[0][3] = __builtin_amdgcn_mfma_scale_f32_16x16x128_f8f6f4(            \
        A0, B3, acc[0][3], 0, 0, 0, SCALE1, 0, SCALE1);                      \
    acc[1][0] = __builtin_amdgcn_mfma_scale_f32_16x16x128_f8f6f4(            \
        A1, B0, acc[1][0], 0, 0, 0, SCALE1, 0, SCALE1);                      \
    acc[1][1] = __builtin_amdgcn_mfma_scale_f32_16x16x128_f8f6f4(            \
        A1, B1, acc[1][1], 0, 0, 0, SCALE1, 0, SCALE1);                      \
    acc[1][2] = __builtin_amdgcn_mfma_scale_f32_16x16x128_f8f6f4(            \
        A1, B2, acc[1][2], 0, 0, 0, SCALE1, 0, SCALE1);                      \
    acc[1][3] = __builtin_amdgcn_mfma_scale_f32_16x16x128_f8f6f4(            \
        A1, B3, acc[1][3], 0, 0, 0, SCALE1, 0, SCALE1);                      \
    acc[2][0] = __builtin_amdgcn_mfma_scale_f32_16x16x128_f8f6f4(            \
        A2, B0, acc[2][0], 0, 0, 0, SCALE1, 0, SCALE1);                      \
    acc[2][1] = __builtin_amdgcn_mfma_scale_f32_16x16x128_f8f6f4(            \
        A2, B1, acc[2][1], 0, 0, 0, SCALE1, 0, SCALE1);                      \
    acc[2][2] = __builtin_amdgcn_mfma_scale_f32_16x16x128_f8f6f4(            \
        A2, B2, acc[2][2], 0, 0, 0, SCALE1, 0, SCALE1);                      \
    acc[2][3] = __builtin_amdgcn_mfma_scale_f32_16x16x128_f8f6f4(            \
        A2, B3, acc[2][3], 0, 0, 0, SCALE1, 0, SCALE1);                      \
    acc[3][0] = __builtin_amdgcn_mfma_scale_f32_16x16x128_f8f6f4(            \
        A3, B0, acc[3][0], 0, 0, 0, SCALE1, 0, SCALE1);                      \
    acc[3][1] = __builtin_amdgcn_mfma_scale_f32_16x16x128_f8f6f4(            \
        A3, B1, acc[3][1], 0, 0, 0, SCALE1, 0, SCALE1);                      \
    acc[3][2] = __builtin_amdgcn_mfma_scale_f32_16x16x128_f8f6f4(            \
        A3, B2, acc[3][2], 0, 0, 0, SCALE1, 0, SCALE1);                      \
    acc[3][3] = __builtin_amdgcn_mfma_scale_f32_16x16x128_f8f6f4(            \
        A3, B3, acc[3][3], 0, 0, 0, SCALE1, 0, SCALE1);                      \
  } while (0)

  // two named fragment sets (rule #20: static, never runtime-indexed)
  int8v xa0, xa1, xa2, xa3, xb0, xb1, xb2, xb3;  // set X
  int8v ya0, ya1, ya2, ya3, yb0, yb1, yb2, yb3;  // set Y

#define LDSET_X(kt)                                                          \
  do {                                                                       \
    LD8(xa0, pa, 0, kt); LD8(xa1, pa, 1, kt);                                \
    LD8(xa2, pa, 2, kt); LD8(xa3, pa, 3, kt);                                \
    LD8(xb0, pb, 0, kt); LD8(xb1, pb, 1, kt);                                \
    LD8(xb2, pb, 2, kt); LD8(xb3, pb, 3, kt);                                \
  } while (0)
#define LDSET_Y(kt)                                                          \
  do {                                                                       \
    LD8(ya0, pa, 0, kt); LD8(ya1, pa, 1, kt);                                \
    LD8(ya2, pa, 2, kt); LD8(ya3, pa, 3, kt);                                \
    LD8(yb0, pb, 0, kt); LD8(yb1, pb, 1, kt);                                \
    LD8(yb2, pb, 2, kt); LD8(yb3, pb, 3, kt);                                \
  } while (0)

  LDSET_X(0);  // prologue
#pragma unroll 1  // rolled: 2 iterations, prefetch distance 1 kt
  for (int t = 0; t < 2; ++t) {
    LDSET_Y(2 * t + 1);                    // issue kt=2t+1 (in flight)
    MFMA16(xa0, xa1, xa2, xa3, xb0, xb1, xb2, xb3);  // compute kt=2t
    if (t == 0) LDSET_X(2);                // issue kt=2 (in flight)
    MFMA16(ya0, ya1, ya2, ya3, yb0, yb1, yb2, yb3);  // compute kt=2t+1
  }

  // epilogue: s = 2*acc; masked cols ((c-r)%B==0) store pos, skip sums.
  // Row sums always; col sums + pos mirror only on off-diagonal tiles.
  const int r0 = rt * 128 + wr * 64;
  const int c0 = ct * 128 + wc * 64;
  float cs[4] = {0.f, 0.f, 0.f, 0.f};  // per-nt column partials (this lane's q)
#pragma unroll
  for (int mt = 0; mt < 4; ++mt) {
    float rs[4] = {0.f, 0.f, 0.f, 0.f};
#pragma unroll
    for (int nt = 0; nt < 4; ++nt) {
      const int c = c0 + nt * 16 + m;  // C layout: col = lane&15
#pragma unroll
      for (int reg = 0; reg < 4; ++reg) {
        const int r = r0 + mt * 16 + q * 4 + reg;  // row = quad*4 + reg
        const float sv = acc[mt][nt][reg] * 2.0f;
        if (((c - r) & (NB - 1)) == 0) {
          pos[r * NV + (c >> 11)] = sv;  // includes j==i (unused later)
          if (!diag) pos[c * NV + (r >> 11)] = sv;
        } else {
          const float e = __expf(sv);
          rs[reg] += e;
          cs[nt] += e;
        }
      }
    }
    // reduce rows across the 16-lane column dimension (m)
#pragma unroll
    for (int off = 1; off < 16; off <<= 1) {
#pragma unroll
      for (int reg = 0; reg < 4; ++reg) rs[reg] += __shfl_xor(rs[reg], off, 64);
    }
    if (m < 4) atomicAdd(&sumexp[r0 + mt * 16 + q * 4 + m], rs[m]);
  }
  if (!diag) {
    // reduce cols across the 4-quad row dimension (q)
#pragma unroll
    for (int nt = 0; nt < 4; ++nt) {
      cs[nt] += __shfl_xor(cs[nt], 16, 64);
      cs[nt] += __shfl_xor(cs[nt], 32, 64);
    }
    if (q == 0) {
#pragma unroll
      for (int nt = 0; nt < 4; ++nt)
        atomicAdd(&sumexp[c0 + nt * 16 + m], cs[nt]);
    }
  }
}

// ---------------- finalize: scalar loss -------------------------------------
__global__ __launch_bounds__(256) void finalize_k(
    const float* __restrict__ sumexp, const float* __restrict__ pos,
    float* __restrict__ out) {
  const int r = blockIdx.x * 256 + threadIdx.x;
  const float se = sumexp[r];
  const int i = r >> 11;  // view index
  float local = 0.0f;
#pragma unroll
  for (int j = 0; j < NV; ++j) {
    if (j == i) continue;
    const float p = pos[r * NV + j];
    local += logf(__expf(p) + se) - p;  // logaddexp(pos, lse_neg) - pos
  }
  local *= (1.0f / NB);
#pragma unroll
  for (int off = 32; off > 0; off >>= 1) local += __shfl_xor(local, off, 64);
  if ((threadIdx.x & 63) == 0) atomicAdd(out, local);
}

extern "C" void kernel_launch(void* const* d_in, const int* in_sizes, int n_in,
                              void* d_out, int out_size, void* d_ws,
                              size_t ws_size, hipStream_t stream) {
  const float* x = (const float*)d_in[0];
  float* out = (float*)d_out;
  char* ws = (char*)d_ws;
  unsigned char* xn = (unsigned char*)ws;                 // 4 MB fp8 (frag layout)
  float* sumexp = (float*)(ws + (size_t)NN * ND);         // 32 KB
  float* pos = (float*)(ws + (size_t)NN * ND + NN * 4);   // 128 KB

  normalize_k<<<NN / 4, 256, 0, stream>>>(x, xn, sumexp, out);
  sim_k<<<64 * 65 / 2, 256, 0, stream>>>(xn, sumexp, pos);
  finalize_k<<<NN / 256, 256, 0, stream>>>(sumexp, pos, out);
}

// Round 11
// 113.035 us; speedup vs baseline: 1.2774x; 1.2774x over previous
//
#include <hip/hip_runtime.h>
#include <hip/hip_fp8.h>

#define NV 4
#define NB 2048
#define ND 512
#define NN 8192
// sim = cos/TEMP, TEMP=0.5 -> scale 2.0

typedef int int8v __attribute__((ext_vector_type(8)));
typedef int int4v __attribute__((ext_vector_type(4)));
typedef float floatx4 __attribute__((ext_vector_type(4)));
#define SCALE1 0x7F7F7F7Fu  // E8M0 bytes 127 -> 2^0 = 1.0

// ============================================================================
// R18 = R14 (best passing: 100.0 µs) with 1024-THREAD BLOCKS (16 waves, 4x4
// wave grid over a 256^2 tile). R17 post-mortem: 2-deep register pipeline
// spilled (WRITE 95 MB, FETCH 70 MB scratch signature) — reg-level K-
// pipelining is dead (measured twice, R10/R17). R15 counters put R14's sim
// at: MFMA 6.4 µs floor, VALU ~15 µs, remainder L2/L3 queueing latency on
// 532 MB of fragment reads from ~8.3K co-resident waves. This round cuts the
// L2-side traffic ~2x with ZERO register/structure change: 4 waves per CU now
// share each A-fragment row-block through L1 (per-kt block read set 64 KB vs
// 32 KB L1), and blocks drop 2080 -> 528 (triangle over 32 tiles of 256).
// Per-wave code is byte-identical to R14. VGPR stays 84; no LDS; no barriers.
// Tripwire: WRITE_SIZE must stay ~4.4 MB.
// ============================================================================

// ---------------- normalize: x[N,D] f32 -> xn fragment-layout fp8 ----------
// fragment layout: xn[R][C][m][b] (R=row>>4, C=k>>5, m=row&15, b=k&31),
// linear = R*8192 + C*512 + m*32 + b. A wave's MFMA operand is 2 KB
// contiguous -> loaded straight from global (4 MB, L2-resident).
__global__ __launch_bounds__(256) void normalize_k(const float* __restrict__ x,
                                                   unsigned char* __restrict__ xn,
                                                   float* __restrict__ sumexp,
                                                   float* __restrict__ out) {
  if (threadIdx.x < 4) sumexp[blockIdx.x * 4 + threadIdx.x] = 0.0f;
  if (blockIdx.x == 0 && threadIdx.x == 0) out[0] = 0.0f;

  const int row = blockIdx.x * 4 + (threadIdx.x >> 6);  // one wave per row
  const int l = threadIdx.x & 63;                        // lane: cols [8l, 8l+8)
  const float4* xr = (const float4*)(x + (size_t)row * ND);
  float4 v0 = xr[l * 2 + 0];
  float4 v1 = xr[l * 2 + 1];
  float ss = v0.x * v0.x + v0.y * v0.y + v0.z * v0.z + v0.w * v0.w +
             v1.x * v1.x + v1.y * v1.y + v1.z * v1.z + v1.w * v1.w;
#pragma unroll
  for (int off = 32; off > 0; off >>= 1) ss += __shfl_xor(ss, off, 64);
  const float inv = 1.0f / fmaxf(sqrtf(ss), 1e-8f);
  union { unsigned char b[8]; uint2 u; } pk;
  pk.b[0] = __hip_fp8_e4m3(v0.x * inv).__x;
  pk.b[1] = __hip_fp8_e4m3(v0.y * inv).__x;
  pk.b[2] = __hip_fp8_e4m3(v0.z * inv).__x;
  pk.b[3] = __hip_fp8_e4m3(v0.w * inv).__x;
  pk.b[4] = __hip_fp8_e4m3(v1.x * inv).__x;
  pk.b[5] = __hip_fp8_e4m3(v1.y * inv).__x;
  pk.b[6] = __hip_fp8_e4m3(v1.z * inv).__x;
  pk.b[7] = __hip_fp8_e4m3(v1.w * inv).__x;
  // k-bytes [8l,8l+8) -> chunk C=l>>2, intra b=(l&3)*8
  const int R = row >> 4, mm = row & 15;
  *(uint2*)(xn + (size_t)R * 8192 + (l >> 2) * 512 + mm * 32 + (l & 3) * 8) =
      pk.u;
}

// ---------------- sim: LDS-free direct-fragment GEMM, 16-wave blocks -------
// Per wave: 64x64 output at (wr*64, wc*64) inside the block's 256^2 tile.
// Per kt: 8 fragments (two dwordx4 each from contiguous 2 KB); 16 MFMA.
__global__ __launch_bounds__(1024) void sim_k(const unsigned char* __restrict__ xn,
                                              float* __restrict__ sumexp,
                                              float* __restrict__ pos) {
  const int tid = threadIdx.x;
  const int l = tid & 63;
  const int m = l & 15, q = l >> 4;
  const int wid = tid >> 6;             // 0..15
  const int wr = wid >> 2, wc = wid & 3;  // 4x4 wave grid

  // XCD swizzle (528 = 8*66, bijective) for L2 locality
  const int bid = (blockIdx.x & 7) * 66 + (blockIdx.x >> 3);
  // triangular decode over 32 tiles: bid -> (rt, ct), rt <= ct
  // (decode verified passing in R8/R11)
  int rt = (int)((65.0f - sqrtf(4225.0f - 8.0f * (float)bid)) * 0.5f);
  rt = rt < 0 ? 0 : (rt > 31 ? 31 : rt);
  while (rt > 0 && (rt * (65 - rt) / 2) > bid) --rt;
  while (rt < 31 && ((rt + 1) * (64 - rt) / 2) <= bid) ++rt;
  const int ct = rt + (bid - rt * (65 - rt) / 2);
  const bool diag = (rt == ct);

  floatx4 acc[4][4] = {};

  // lane base inside a fragment block: chunk q (512 B), row m (32 B)
  const unsigned char* pa =
      xn + (size_t)(rt * 16 + wr * 4) * 8192 + q * 512 + m * 32;
  const unsigned char* pb =
      xn + (size_t)(ct * 16 + wc * 4) * 8192 + q * 512 + m * 32;

#define LDFRAG(dst, base, mt, kt)                                            \
  do {                                                                       \
    const unsigned char* p_ = (base) + (mt) * 8192 + (kt) * 2048;            \
    dst = __builtin_shufflevector(*(const int4v*)(p_),                       \
                                  *(const int4v*)(p_ + 16),                  \
                                  0, 1, 2, 3, 4, 5, 6, 7);                   \
  } while (0)

#pragma unroll 1  // rolled: 64 hoisted loads would spill (R10/R17 lesson)
  for (int kt = 0; kt < 4; ++kt) {
    int8v af0, af1, af2, af3, bf0, bf1, bf2, bf3;
    LDFRAG(af0, pa, 0, kt);
    LDFRAG(af1, pa, 1, kt);
    LDFRAG(af2, pa, 2, kt);
    LDFRAG(af3, pa, 3, kt);
    LDFRAG(bf0, pb, 0, kt);
    LDFRAG(bf1, pb, 1, kt);
    LDFRAG(bf2, pb, 2, kt);
    LDFRAG(bf3, pb, 3, kt);
#define MFMA_ROW(mt, afv)                                                    \
  acc[mt][0] = __builtin_amdgcn_mfma_scale_f32_16x16x128_f8f6f4(             \
      afv, bf0, acc[mt][0], 0, 0, 0, SCALE1, 0, SCALE1);                     \
  acc[mt][1] = __builtin_amdgcn_mfma_scale_f32_16x16x128_f8f6f4(             \
      afv, bf1, acc[mt][1], 0, 0, 0, SCALE1, 0, SCALE1);                     \
  acc[mt][2] = __builtin_amdgcn_mfma_scale_f32_16x16x128_f8f6f4(             \
      afv, bf2, acc[mt][2], 0, 0, 0, SCALE1, 0, SCALE1);                     \
  acc[mt][3] = __builtin_amdgcn_mfma_scale_f32_16x16x128_f8f6f4(             \
      afv, bf3, acc[mt][3], 0, 0, 0, SCALE1, 0, SCALE1)
    MFMA_ROW(0, af0);
    MFMA_ROW(1, af1);
    MFMA_ROW(2, af2);
    MFMA_ROW(3, af3);
#undef MFMA_ROW
  }

  // epilogue: s = 2*acc; masked cols ((c-r)%B==0) store pos, skip sums.
  // Row sums always; col sums + pos mirror only on off-diagonal tiles.
  // (Diag blocks compute the full 256^2 tile incl. both triangles — same
  // redundancy/semantics as R14's diag handling, just bigger tile.)
  const int r0 = rt * 256 + wr * 64;
  const int c0 = ct * 256 + wc * 64;
  float cs[4] = {0.f, 0.f, 0.f, 0.f};  // per-nt column partials (this lane's q)
#pragma unroll
  for (int mt = 0; mt < 4; ++mt) {
    float rs[4] = {0.f, 0.f, 0.f, 0.f};
#pragma unroll
    for (int nt = 0; nt < 4; ++nt) {
      const int c = c0 + nt * 16 + m;  // C layout: col = lane&15
#pragma unroll
      for (int reg = 0; reg < 4; ++reg) {
        const int r = r0 + mt * 16 + q * 4 + reg;  // row = quad*4 + reg
        const float sv = acc[mt][nt][reg] * 2.0f;
        if (((c - r) & (NB - 1)) == 0) {
          pos[r * NV + (c >> 11)] = sv;  // includes j==i (unused later)
          if (!diag) pos[c * NV + (r >> 11)] = sv;
        } else {
          const float e = __expf(sv);
          rs[reg] += e;
          cs[nt] += e;
        }
      }
    }
    // reduce rows across the 16-lane column dimension (m)
#pragma unroll
    for (int off = 1; off < 16; off <<= 1) {
#pragma unroll
      for (int reg = 0; reg < 4; ++reg) rs[reg] += __shfl_xor(rs[reg], off, 64);
    }
    if (m < 4) atomicAdd(&sumexp[r0 + mt * 16 + q * 4 + m], rs[m]);
  }
  if (!diag) {
    // reduce cols across the 4-quad row dimension (q)
#pragma unroll
    for (int nt = 0; nt < 4; ++nt) {
      cs[nt] += __shfl_xor(cs[nt], 16, 64);
      cs[nt] += __shfl_xor(cs[nt], 32, 64);
    }
    if (q == 0) {
#pragma unroll
      for (int nt = 0; nt < 4; ++nt)
        atomicAdd(&sumexp[c0 + nt * 16 + m], cs[nt]);
    }
  }
}

// ---------------- finalize: scalar loss -------------------------------------
__global__ __launch_bounds__(256) void finalize_k(
    const float* __restrict__ sumexp, const float* __restrict__ pos,
    float* __restrict__ out) {
  const int r = blockIdx.x * 256 + threadIdx.x;
  const float se = sumexp[r];
  const int i = r >> 11;  // view index
  float local = 0.0f;
#pragma unroll
  for (int j = 0; j < NV; ++j) {
    if (j == i) continue;
    const float p = pos[r * NV + j];
    local += logf(__expf(p) + se) - p;  // logaddexp(pos, lse_neg) - pos
  }
  local *= (1.0f / NB);
#pragma unroll
  for (int off = 32; off > 0; off >>= 1) local += __shfl_xor(local, off, 64);
  if ((threadIdx.x & 63) == 0) atomicAdd(out, local);
}

extern "C" void kernel_launch(void* const* d_in, const int* in_sizes, int n_in,
                              void* d_out, int out_size, void* d_ws,
                              size_t ws_size, hipStream_t stream) {
  const float* x = (const float*)d_in[0];
  float* out = (float*)d_out;
  char* ws = (char*)d_ws;
  unsigned char* xn = (unsigned char*)ws;                 // 4 MB fp8 (frag layout)
  float* sumexp = (float*)(ws + (size_t)NN * ND);         // 32 KB
  float* pos = (float*)(ws + (size_t)NN * ND + NN * 4);   // 128 KB

  normalize_k<<<NN / 4, 256, 0, stream>>>(x, xn, sumexp, out);
  sim_k<<<32 * 33 / 2, 1024, 0, stream>>>(xn, sumexp, pos);
  finalize_k<<<NN / 256, 256, 0, stream>>>(sumexp, pos, out);
}

// Round 12
// 97.888 us; speedup vs baseline: 1.4751x; 1.1547x over previous
//
#include <hip/hip_runtime.h>
#include <hip/hip_fp8.h>

#define NV 4
#define NB 2048
#define ND 512
#define NN 8192
// sim = cos/TEMP, TEMP=0.5 -> scale 2.0

typedef int int8v __attribute__((ext_vector_type(8)));
typedef int int4v __attribute__((ext_vector_type(4)));
typedef float floatx4 __attribute__((ext_vector_type(4)));
#define SCALE1 0x7F7F7F7Fu  // E8M0 bytes 127 -> 2^0 = 1.0

// ============================================================================
// R19 = R14 (best passing: 100.0 µs) + two zero-register scheduling micro-opts
// in the kt loop. Session record: every structural restructure lost to R14
// (LDS 2-phase 48-51, counted-vmcnt 58, full-K LDS 69, cooperative 150,
// reg-pipeline spill 95, 16-wave blocks 57). R14 model: MFMA 6.4 µs floor,
// VALU ~12, L1-filtered L2 stream ~8 — overlapped; rest is per-kt first-use
// load latency. Micro-opts:
//  1. interleaved frag loads (af0,bf0,af1,bf1,...): first MFMA waits on
//     loads #1-2, not #1 and #5 — shorter head-of-kt waitcnt.
//  2. s_setprio(1) around the MFMA cluster (T5): waves here are barrier-free
//     and desynced — the attn-like regime where setprio measured +4-7%
//     (m191), not the lockstep-GEMM null regime (m190).
// Everything else byte-identical to R14. Tripwires: VGPR ~84, WRITE ~4.4 MB.
// ============================================================================

// ---------------- normalize: x[N,D] f32 -> xn fragment-layout fp8 ----------
// fragment layout: xn[R][C][m][b] (R=row>>4, C=k>>5, m=row&15, b=k&31),
// linear = R*8192 + C*512 + m*32 + b. A wave's MFMA operand is 2 KB
// contiguous -> loaded straight from global (4 MB, L2-resident).
__global__ __launch_bounds__(256) void normalize_k(const float* __restrict__ x,
                                                   unsigned char* __restrict__ xn,
                                                   float* __restrict__ sumexp,
                                                   float* __restrict__ out) {
  if (threadIdx.x < 4) sumexp[blockIdx.x * 4 + threadIdx.x] = 0.0f;
  if (blockIdx.x == 0 && threadIdx.x == 0) out[0] = 0.0f;

  const int row = blockIdx.x * 4 + (threadIdx.x >> 6);  // one wave per row
  const int l = threadIdx.x & 63;                        // lane: cols [8l, 8l+8)
  const float4* xr = (const float4*)(x + (size_t)row * ND);
  float4 v0 = xr[l * 2 + 0];
  float4 v1 = xr[l * 2 + 1];
  float ss = v0.x * v0.x + v0.y * v0.y + v0.z * v0.z + v0.w * v0.w +
             v1.x * v1.x + v1.y * v1.y + v1.z * v1.z + v1.w * v1.w;
#pragma unroll
  for (int off = 32; off > 0; off >>= 1) ss += __shfl_xor(ss, off, 64);
  const float inv = 1.0f / fmaxf(sqrtf(ss), 1e-8f);
  union { unsigned char b[8]; uint2 u; } pk;
  pk.b[0] = __hip_fp8_e4m3(v0.x * inv).__x;
  pk.b[1] = __hip_fp8_e4m3(v0.y * inv).__x;
  pk.b[2] = __hip_fp8_e4m3(v0.z * inv).__x;
  pk.b[3] = __hip_fp8_e4m3(v0.w * inv).__x;
  pk.b[4] = __hip_fp8_e4m3(v1.x * inv).__x;
  pk.b[5] = __hip_fp8_e4m3(v1.y * inv).__x;
  pk.b[6] = __hip_fp8_e4m3(v1.z * inv).__x;
  pk.b[7] = __hip_fp8_e4m3(v1.w * inv).__x;
  // k-bytes [8l,8l+8) -> chunk C=l>>2, intra b=(l&3)*8
  const int R = row >> 4, mm = row & 15;
  *(uint2*)(xn + (size_t)R * 8192 + (l >> 2) * 512 + mm * 32 + (l & 3) * 8) =
      pk.u;
}

// ---------------- sim: barrier-free, LDS-free, direct-fragment GEMM --------
// Per wave: 64x64 output at (wr*64, wc*64) of the 128^2 tile. Per kt:
// 8 fragments (two dwordx4 each from a contiguous 2 KB run); 16 MFMA.
__global__ __launch_bounds__(256) void sim_k(const unsigned char* __restrict__ xn,
                                             float* __restrict__ sumexp,
                                             float* __restrict__ pos) {
  const int tid = threadIdx.x;
  const int l = tid & 63;
  const int m = l & 15, q = l >> 4;
  const int wr = (tid >> 6) >> 1, wc = (tid >> 6) & 1;

  // XCD swizzle (2080 = 8*260, bijective) for L2 locality
  const int bid = (blockIdx.x & 7) * 260 + (blockIdx.x >> 3);
  // triangular decode: bid -> (rt, ct), rt <= ct
  int rt = (int)((129.0f - sqrtf(16641.0f - 8.0f * (float)bid)) * 0.5f);
  rt = rt < 0 ? 0 : (rt > 63 ? 63 : rt);
  while (rt > 0 && (rt * 64 - rt * (rt - 1) / 2) > bid) --rt;
  while (rt < 63 && ((rt + 1) * 64 - (rt + 1) * rt / 2) <= bid) ++rt;
  const int ct = rt + (bid - (rt * 64 - rt * (rt - 1) / 2));
  const bool diag = (rt == ct);

  floatx4 acc[4][4] = {};

  // lane base inside a fragment block: chunk q (512 B), row m (32 B)
  const unsigned char* pa =
      xn + (size_t)(rt * 8 + wr * 4) * 8192 + q * 512 + m * 32;
  const unsigned char* pb =
      xn + (size_t)(ct * 8 + wc * 4) * 8192 + q * 512 + m * 32;

#define LDFRAG(dst, base, mt, kt)                                            \
  do {                                                                       \
    const unsigned char* p_ = (base) + (mt) * 8192 + (kt) * 2048;            \
    dst = __builtin_shufflevector(*(const int4v*)(p_),                       \
                                  *(const int4v*)(p_ + 16),                  \
                                  0, 1, 2, 3, 4, 5, 6, 7);                   \
  } while (0)

#pragma unroll 1  // rolled: 64 hoisted loads would spill (R10/R17 lesson)
  for (int kt = 0; kt < 4; ++kt) {
    int8v af0, af1, af2, af3, bf0, bf1, bf2, bf3;
    // interleaved issue: first MFMA's operands are loads #1-2, not #1 and #5
    LDFRAG(af0, pa, 0, kt);
    LDFRAG(bf0, pb, 0, kt);
    LDFRAG(af1, pa, 1, kt);
    LDFRAG(bf1, pb, 1, kt);
    LDFRAG(af2, pa, 2, kt);
    LDFRAG(bf2, pb, 2, kt);
    LDFRAG(af3, pa, 3, kt);
    LDFRAG(bf3, pb, 3, kt);
    __builtin_amdgcn_s_setprio(1);
#define MFMA_ROW(mt, afv)                                                    \
  acc[mt][0] = __builtin_amdgcn_mfma_scale_f32_16x16x128_f8f6f4(             \
      afv, bf0, acc[mt][0], 0, 0, 0, SCALE1, 0, SCALE1);                     \
  acc[mt][1] = __builtin_amdgcn_mfma_scale_f32_16x16x128_f8f6f4(             \
      afv, bf1, acc[mt][1], 0, 0, 0, SCALE1, 0, SCALE1);                     \
  acc[mt][2] = __builtin_amdgcn_mfma_scale_f32_16x16x128_f8f6f4(             \
      afv, bf2, acc[mt][2], 0, 0, 0, SCALE1, 0, SCALE1);                     \
  acc[mt][3] = __builtin_amdgcn_mfma_scale_f32_16x16x128_f8f6f4(             \
      afv, bf3, acc[mt][3], 0, 0, 0, SCALE1, 0, SCALE1)
    MFMA_ROW(0, af0);
    MFMA_ROW(1, af1);
    MFMA_ROW(2, af2);
    MFMA_ROW(3, af3);
#undef MFMA_ROW
    __builtin_amdgcn_s_setprio(0);
  }

  // epilogue: s = 2*acc; masked cols ((c-r)%B==0) store pos, skip sums.
  // Row sums always; col sums + pos mirror only on off-diagonal tiles.
  const int r0 = rt * 128 + wr * 64;
  const int c0 = ct * 128 + wc * 64;
  float cs[4] = {0.f, 0.f, 0.f, 0.f};  // per-nt column partials (this lane's q)
#pragma unroll
  for (int mt = 0; mt < 4; ++mt) {
    float rs[4] = {0.f, 0.f, 0.f, 0.f};
#pragma unroll
    for (int nt = 0; nt < 4; ++nt) {
      const int c = c0 + nt * 16 + m;  // C layout: col = lane&15
#pragma unroll
      for (int reg = 0; reg < 4; ++reg) {
        const int r = r0 + mt * 16 + q * 4 + reg;  // row = quad*4 + reg
        const float sv = acc[mt][nt][reg] * 2.0f;
        if (((c - r) & (NB - 1)) == 0) {
          pos[r * NV + (c >> 11)] = sv;  // includes j==i (unused later)
          if (!diag) pos[c * NV + (r >> 11)] = sv;
        } else {
          const float e = __expf(sv);
          rs[reg] += e;
          cs[nt] += e;
        }
      }
    }
    // reduce rows across the 16-lane column dimension (m)
#pragma unroll
    for (int off = 1; off < 16; off <<= 1) {
#pragma unroll
      for (int reg = 0; reg < 4; ++reg) rs[reg] += __shfl_xor(rs[reg], off, 64);
    }
    if (m < 4) atomicAdd(&sumexp[r0 + mt * 16 + q * 4 + m], rs[m]);
  }
  if (!diag) {
    // reduce cols across the 4-quad row dimension (q)
#pragma unroll
    for (int nt = 0; nt < 4; ++nt) {
      cs[nt] += __shfl_xor(cs[nt], 16, 64);
      cs[nt] += __shfl_xor(cs[nt], 32, 64);
    }
    if (q == 0) {
#pragma unroll
      for (int nt = 0; nt < 4; ++nt)
        atomicAdd(&sumexp[c0 + nt * 16 + m], cs[nt]);
    }
  }
}

// ---------------- finalize: scalar loss -------------------------------------
__global__ __launch_bounds__(256) void finalize_k(
    const float* __restrict__ sumexp, const float* __restrict__ pos,
    float* __restrict__ out) {
  const int r = blockIdx.x * 256 + threadIdx.x;
  const float se = sumexp[r];
  const int i = r >> 11;  // view index
  float local = 0.0f;
#pragma unroll
  for (int j = 0; j < NV; ++j) {
    if (j == i) continue;
    const float p = pos[r * NV + j];
    local += logf(__expf(p) + se) - p;  // logaddexp(pos, lse_neg) - pos
  }
  local *= (1.0f / NB);
#pragma unroll
  for (int off = 32; off > 0; off >>= 1) local += __shfl_xor(local, off, 64);
  if ((threadIdx.x & 63) == 0) atomicAdd(out, local);
}

extern "C" void kernel_launch(void* const* d_in, const int* in_sizes, int n_in,
                              void* d_out, int out_size, void* d_ws,
                              size_t ws_size, hipStream_t stream) {
  const float* x = (const float*)d_in[0];
  float* out = (float*)d_out;
  char* ws = (char*)d_ws;
  unsigned char* xn = (unsigned char*)ws;                 // 4 MB fp8 (frag layout)
  float* sumexp = (float*)(ws + (size_t)NN * ND);         // 32 KB
  float* pos = (float*)(ws + (size_t)NN * ND + NN * 4);   // 128 KB

  normalize_k<<<NN / 4, 256, 0, stream>>>(x, xn, sumexp, out);
  sim_k<<<64 * 65 / 2, 256, 0, stream>>>(xn, sumexp, pos);
  finalize_k<<<NN / 256, 256, 0, stream>>>(sumexp, pos, out);
}